// Round 4
// baseline (305.726 us; speedup 1.0000x reference)
//
#include <hip/hip_runtime.h>
#include <math.h>

#define EPSV 1e-5f
#define EPB3 4096  // edges per bucket-pass block (196 blocks, proven config)
#define NBP 256    // buckets of 256 nodes (N <= 65536; src packed in 16 bits)
#define CAP 6144   // per-bucket edgeTmp slab capacity (mean ~4081, +32 sigma)
#define CAPS (CAP + 768)  // padded sorted-slab capacity (pad <=3 per node)

typedef short s16x8 __attribute__((ext_vector_type(8)));
typedef float f32x4 __attribute__((ext_vector_type(4)));
typedef unsigned short u16;

#define MFMA(a, b, c) __builtin_amdgcn_mfma_f32_16x16x32_bf16(a, b, c, 0, 0, 0)

__device__ inline u16 f2bf(float f) {
    unsigned u = __float_as_uint(f);
    return (u16)((u + 0x7FFF + ((u >> 16) & 1)) >> 16);
}
__device__ inline float bf2f(u16 h) { return __uint_as_float(((unsigned)h) << 16); }

__device__ inline void split8(const float4& a, const float4& b, s16x8& hv, s16x8& lv) {
    float f[8] = {a.x, a.y, a.z, a.w, b.x, b.y, b.z, b.w};
#pragma unroll
    for (int i = 0; i < 8; ++i) {
        u16 h = f2bf(f[i]);
        hv[i] = (short)h;
        lv[i] = (short)f2bf(f[i] - bf2f(h));
    }
}

__device__ inline uint4 pack8(const float* v) {
    uint4 r;
    r.x = (unsigned)f2bf(v[0]) | ((unsigned)f2bf(v[1]) << 16);
    r.y = (unsigned)f2bf(v[2]) | ((unsigned)f2bf(v[3]) << 16);
    r.z = (unsigned)f2bf(v[4]) | ((unsigned)f2bf(v[5]) << 16);
    r.w = (unsigned)f2bf(v[6]) | ((unsigned)f2bf(v[7]) << 16);
    return r;
}

// ---------------- pre1: bucket partition + weight prep (merged) ----------------
// blocks [0, NB1): bucket3 body. blocks [NB1, NB1+449*L): wprep body.
__global__ __launch_bounds__(512) void k_pre1(
    const int* __restrict__ src, const int* __restrict__ dst, int E,
    int* __restrict__ bucketCursor, unsigned* __restrict__ edgeTmp,
    const float* __restrict__ pre_w, const float* __restrict__ post_w,
    const float* __restrict__ post_b, const float* __restrict__ lin_w,
    const float* __restrict__ lin_b, u16* __restrict__ WpT_hi,
    u16* __restrict__ WpT_lo, u16* __restrict__ WT_hi, u16* __restrict__ WT_lo,
    float* __restrict__ bpp, int NB1) {
    __shared__ int cnt[NBP], loff[NBP], lpos[NBP], gbase[NBP], sbuf[NBP];
    __shared__ unsigned stage[EPB3];
    int t = threadIdx.x;
    if ((int)blockIdx.x < NB1) {
        // ---- bucket3 body (verbatim) ----
        int base = blockIdx.x * EPB3;
        int cntE = min(EPB3, E - base);
        if (t < NBP) cnt[t] = 0;
        __syncthreads();
        unsigned ed[8];
#pragma unroll
        for (int j = 0; j < 8; ++j) {
            int idx = j * 512 + t;
            if (idx < cntE) {
                int e = base + idx;
                unsigned s = (unsigned)src[e];
                unsigned d = (unsigned)dst[e];
                ed[j] = ((d >> 8) << 24) | ((d & 255u) << 16) | s;
                atomicAdd(&cnt[d >> 8], 1);
            } else ed[j] = 0xFFFFFFFFu;
        }
        __syncthreads();
        if (t < NBP) sbuf[t] = cnt[t];
        __syncthreads();
        for (int o = 1; o < NBP; o <<= 1) {
            int v = 0;
            if (t < NBP && t >= o) v = sbuf[t - o];
            __syncthreads();
            if (t < NBP) sbuf[t] += v;
            __syncthreads();
        }
        if (t < NBP) {
            loff[t] = sbuf[t] - cnt[t];
            lpos[t] = sbuf[t] - cnt[t];
            gbase[t] = (cnt[t] > 0) ? atomicAdd(&bucketCursor[t], cnt[t]) : 0;
        }
        __syncthreads();
#pragma unroll
        for (int j = 0; j < 8; ++j) {
            if (ed[j] != 0xFFFFFFFFu) {
                int b = ed[j] >> 24;
                int p = atomicAdd(&lpos[b], 1);
                stage[p] = ed[j];
            }
        }
        __syncthreads();
        for (int i = t; i < cntE; i += 512) {
            unsigned pr = stage[i];
            int b = pr >> 24;
            int pos = gbase[b] + (i - loff[b]);
            if (pos < CAP) edgeTmp[(size_t)b * CAP + pos] = pr;
        }
        return;
    }
    // ---- wprep body ----
    int wq = blockIdx.x - NB1;
    int l = wq / 449;
    int bx = wq - l * 449;
    if (bx < 320) {
        if (t < 192) {
            int k = bx, j = t;
            int third = j >> 6, c = j & 63;
            float out = 0.f;
            int r = -1;
            if (k < 64) r = (third == 0) ? k : -1;
            else        r = 64 + third * 256 + (k - 64);
            if (r >= 0) {
                const float* pw = post_w + (size_t)(l * 832 + r) * 64;
                const float* lw = lin_w + (size_t)l * 64 * 64;
                float s = 0.f;
                for (int kk = 0; kk < 64; ++kk) s += pw[kk] * lw[kk * 64 + c];
                out = s;
            }
            u16 h = f2bf(out);
            size_t o = ((size_t)l * 192 + j) * 320 + k;
            WT_hi[o] = h;
            WT_lo[o] = f2bf(out - bf2f(h));
        }
    } else if (bx < 448) {
        if (t < 64) {
            int c = bx - 320, k = t;
            float v = pre_w[(size_t)l * 8192 + (size_t)(k + (c >= 64 ? 64 : 0)) * 64 + (c & 63)];
            u16 h = f2bf(v);
            size_t o = ((size_t)l * 128 + c) * 64 + k;
            WpT_hi[o] = h;
            WpT_lo[o] = f2bf(v - bf2f(h));
        }
    } else {
        if (t < 64) {
            int c = t;
            const float* pb = post_b + l * 64;
            const float* lw = lin_w + (size_t)l * 64 * 64;
            float s = lin_b[l * 64 + c];
            for (int k = 0; k < 64; ++k) s += pb[k] * lw[k * 64 + c];
            bpp[l * 64 + c] = s;
        }
    }
}

// ---------------- pre2: counting-sort + layer-0 gemm1 (merged) ----------------
// blocks [0, NB): csort body. blocks [NB, NB+gblk): gemm1 body (t<256, one barrier).
__global__ __launch_bounds__(512) void k_pre2(
    const unsigned* __restrict__ edgeTmp, const int* __restrict__ bucketCur,
    int* __restrict__ deg, int* __restrict__ offs, float* __restrict__ lsum,
    u16* __restrict__ srcSorted,
    const float* __restrict__ x, const u16* __restrict__ WpT_hi,
    const u16* __restrict__ WpT_lo, const float* __restrict__ pre_b,
    u16* __restrict__ Ph, u16* __restrict__ Qh,
    int N, int E, int NB) {
    __shared__ __align__(16) char smem[55296];
    int t = threadIdx.x;
    if ((int)blockIdx.x < NB) {
        // ---- csort body: per-bucket padded slabs ----
        int* scnt = (int*)smem;
        int* sbuf = (int*)(smem + 1024);
        int* lcur = (int*)(smem + 2048);
        int* lofs = (int*)(smem + 3072);
        float* fred = (float*)(smem + 4096);
        u16* stageSrc = (u16*)(smem + 5120);
        int* cntPs = (int*)(smem + 5120 + CAPS * 2);
        int b = blockIdx.x;
        int n0 = b << 8;
        int nodes = min(256, N - n0);
        if (t < NBP) { lcur[t] = 0; scnt[t] = 0; }
        __syncthreads();
        int cnt = min(bucketCur[b], CAP);
        const unsigned* ebase = edgeTmp + (size_t)b * CAP;
        for (int i = t; i < cnt; i += 512) atomicAdd(&lcur[(ebase[i] >> 16) & 255], 1);
        __syncthreads();
        float ls = 0.f;
        int d = 0, dP = 0;
        if (t < nodes) {
            d = lcur[t];
            deg[n0 + t] = d;
            ls = logf(fmaxf((float)d, 1.f) + 1.f);
            dP = (d + 3) & ~3;
        }
        if (t < 256) fred[t] = ls;
        if (t < NBP) sbuf[t] = dP;
        __syncthreads();
        for (int o = 1; o < NBP; o <<= 1) {
            int v = 0;
            if (t < NBP && t >= o) v = sbuf[t - o];
            __syncthreads();
            if (t < NBP) sbuf[t] += v;
            __syncthreads();
        }
        if (t < NBP) lofs[t] = sbuf[t] - dP;
        if (t < nodes) offs[n0 + t] = b * CAPS + (sbuf[t] - dP);
        if (t == NBP - 1) *cntPs = sbuf[t];
        __syncthreads();
        for (int o = 128; o > 0; o >>= 1) {
            if (t < o) fred[t] += fred[t + o];
            __syncthreads();
        }
        if (t == 0) atomicAdd(lsum, fred[0]);
        for (int i = t; i < cnt; i += 512) {
            unsigned p = ebase[i];
            int dl = (p >> 16) & 255;
            int r = atomicAdd(&scnt[dl], 1);
            stageSrc[lofs[dl] + r] = (u16)(p & 0xFFFFu);
        }
        __syncthreads();
        if (t < nodes && (d & 3)) {
            int lp = lofs[t];
            u16 lastv = stageSrc[lp + d - 1];
            for (int k = d; k < dP; ++k) stageSrc[lp + k] = lastv;
        }
        __syncthreads();
        int cntP = *cntPs;
        for (int i = t; i < cntP; i += 512) srcSorted[(size_t)b * CAPS + i] = stageSrc[i];
        return;
    }
    // ---- gemm1 body: 64 rows, threads 0..255, ONE hoisted barrier ----
    u16* Ah = (u16*)smem;            // 64*72 u16 = 9216 B
    u16* Al = (u16*)(smem + 9216);
    u16* Bh = (u16*)(smem + 18432);  // 128*72 u16 = 18432 B
    u16* Bl = (u16*)(smem + 36864);
    int rows0 = ((int)blockIdx.x - NB) * 64;
    int wid = t >> 6, lane = t & 63;
    int quad = lane >> 4, l16 = lane & 15;
    int wm = wid & 1, wn = wid >> 1;
    if (t < 256) {
#pragma unroll
        for (int it = 0; it < 2; ++it) {
            int task = it * 256 + t;
            int r = task >> 3, seg = task & 7;
            int row = rows0 + r;
            float4 v0 = make_float4(0.f, 0.f, 0.f, 0.f), v1 = v0;
            if (row < N) {
                v0 = *(const float4*)&x[(size_t)row * 64 + seg * 8];
                v1 = *(const float4*)&x[(size_t)row * 64 + seg * 8 + 4];
            }
            s16x8 hv, lv;
            split8(v0, v1, hv, lv);
            *(s16x8*)&Ah[r * 72 + seg * 8] = hv;
            *(s16x8*)&Al[r * 72 + seg * 8] = lv;
        }
#pragma unroll
        for (int it = 0; it < 4; ++it) {
            int task = it * 256 + t;
            int c = task >> 3, seg = task & 7;
            *(s16x8*)&Bh[c * 72 + seg * 8] = *(const s16x8*)&WpT_hi[(size_t)c * 64 + seg * 8];
            *(s16x8*)&Bl[c * 72 + seg * 8] = *(const s16x8*)&WpT_lo[(size_t)c * 64 + seg * 8];
        }
    }
    __syncthreads();
    if (t < 256) {
        f32x4 acc[2][4];
#pragma unroll
        for (int mt = 0; mt < 2; ++mt)
#pragma unroll
            for (int tt = 0; tt < 4; ++tt) acc[mt][tt] = (f32x4){0.f, 0.f, 0.f, 0.f};
#pragma unroll
        for (int c = 0; c < 2; ++c) {
            s16x8 ah[2], al[2];
#pragma unroll
            for (int mt = 0; mt < 2; ++mt) {
                int r = wm * 32 + mt * 16 + l16;
                ah[mt] = *(s16x8*)&Ah[r * 72 + c * 32 + quad * 8];
                al[mt] = *(s16x8*)&Al[r * 72 + c * 32 + quad * 8];
            }
#pragma unroll
            for (int tt = 0; tt < 4; ++tt) {
                int cc = wn * 64 + tt * 16 + l16;
                s16x8 bh = *(s16x8*)&Bh[cc * 72 + c * 32 + quad * 8];
                s16x8 bl = *(s16x8*)&Bl[cc * 72 + c * 32 + quad * 8];
#pragma unroll
                for (int mt = 0; mt < 2; ++mt) {
                    acc[mt][tt] = MFMA(ah[mt], bh, acc[mt][tt]);
                    acc[mt][tt] = MFMA(ah[mt], bl, acc[mt][tt]);
                    if (wn == 0) acc[mt][tt] = MFMA(al[mt], bh, acc[mt][tt]);
                }
            }
        }
#pragma unroll
        for (int mt = 0; mt < 2; ++mt)
#pragma unroll
            for (int tt = 0; tt < 4; ++tt) {
                int col = wn * 64 + tt * 16 + l16;
#pragma unroll
                for (int r = 0; r < 4; ++r) {
                    int row = rows0 + wm * 32 + mt * 16 + quad * 4 + r;
                    if (row >= N) continue;
                    float v = acc[mt][tt][r];
                    if (col < 64) Ph[(size_t)row * 64 + col] = f2bf(v + pre_b[col]);
                    else          Qh[(size_t)row * 64 + (col - 64)] = f2bf(v);
                }
            }
    }
}

// ---------------- fused per-layer kernel: agg + gemm2 + (doNext) gemm1 ----------------
// Agg phase: 4 threads/node, 16 feats/thread, distribution chosen so thread t
// computes exactly the AGGh elements it stages in phase 2 (block-local scratch,
// L1-warm; no cross-thread or cross-block AGGh dependency). Edge-order summation
// and pad-correction are bit-identical to the standalone v4 k_agg.
__global__ __launch_bounds__(512) void k_layer(
    const float* __restrict__ hIn, const u16* __restrict__ Ph,
    const u16* __restrict__ Qh, const int* __restrict__ offs,
    const int* __restrict__ degp, const u16* __restrict__ ss,
    u16* __restrict__ AGGh,
    const u16* __restrict__ WT_hi, const u16* __restrict__ WT_lo,
    const float* __restrict__ bpp, const float* __restrict__ lsum,
    float* __restrict__ hOut, int doNext,
    const u16* __restrict__ WpN_hi, const u16* __restrict__ WpN_lo,
    const float* __restrict__ pre_bN, u16* __restrict__ PhN,
    u16* __restrict__ QhN, int M) {
    __shared__ u16 Ah[128 * 40], Al[128 * 40];  // [row][k-chunk 32], pitch 40
    __shared__ u16 Bh[192 * 40], Bl[192 * 40];  // [col][k-chunk 32], pitch 40
    int t = threadIdx.x, wid = t >> 6, lane = t & 63;
    int rows0 = blockIdx.x * 128;
    int quad = lane >> 4, l16 = lane & 15;
    int wm = wid & 3, wn = wid >> 2;

    // ---- Phase 0: aggregation for this block's 128 nodes ----
    {
        int nloc = t >> 2;
        int node = rows0 + nloc;
        int fb = (t & 3) << 3;  // feature base: 0,8,16,24
        int nc2 = min(node, M - 1);
        int beg = offs[nc2];
        int d = (node < M) ? degp[nc2] : 0;
        int dP = (d + 3) & ~3;
        float sum[16], sq[16], mx[16], mn[16];
#pragma unroll
        for (int i = 0; i < 16; ++i) {
            sum[i] = 0.f; sq[i] = 0.f; mx[i] = -3.4e38f; mn[i] = 3.4e38f;
        }
        const u16* ssb = ss + beg;
        for (int e0 = 0; e0 < dP; e0 += 4) {
            uint2 sw = *(const uint2*)(ssb + e0);
            unsigned sid[4] = {sw.x & 0xFFFFu, sw.x >> 16, sw.y & 0xFFFFu, sw.y >> 16};
#pragma unroll
            for (int j = 0; j < 4; ++j) {
                const u16* qr = Qh + ((size_t)sid[j] << 6) + fb;
                uint4 qa = *(const uint4*)qr;
                uint4 qb = *(const uint4*)(qr + 32);
                unsigned wd[8] = {qa.x, qa.y, qa.z, qa.w, qb.x, qb.y, qb.z, qb.w};
#pragma unroll
                for (int k = 0; k < 8; ++k) {
                    float v0 = __uint_as_float(wd[k] << 16);
                    float v1 = __uint_as_float(wd[k] & 0xFFFF0000u);
                    sum[2 * k] += v0; sq[2 * k] = fmaf(v0, v0, sq[2 * k]);
                    mx[2 * k] = fmaxf(mx[2 * k], v0); mn[2 * k] = fminf(mn[2 * k], v0);
                    sum[2 * k + 1] += v1; sq[2 * k + 1] = fmaf(v1, v1, sq[2 * k + 1]);
                    mx[2 * k + 1] = fmaxf(mx[2 * k + 1], v1); mn[2 * k + 1] = fminf(mn[2 * k + 1], v1);
                }
            }
        }
        if (d & 3) {  // subtract the (dP-d) duplicated pad edges from sum/sq
            unsigned s = ssb[d - 1];
            const u16* qr = Qh + ((size_t)s << 6) + fb;
            uint4 qa = *(const uint4*)qr;
            uint4 qb = *(const uint4*)(qr + 32);
            unsigned wd[8] = {qa.x, qa.y, qa.z, qa.w, qb.x, qb.y, qb.z, qb.w};
            float pf = (float)(dP - d);
#pragma unroll
            for (int k = 0; k < 8; ++k) {
                float v0 = __uint_as_float(wd[k] << 16);
                float v1 = __uint_as_float(wd[k] & 0xFFFF0000u);
                float t0 = pf * v0, t1 = pf * v1;
                sum[2 * k] -= t0; sq[2 * k] = fmaf(-t0, v0, sq[2 * k]);
                sum[2 * k + 1] -= t1; sq[2 * k + 1] = fmaf(-t1, v1, sq[2 * k + 1]);
            }
        }
        float dc = fmaxf((float)d, 1.f);
        float inv = 1.f / dc;
        const u16* pr = Ph + ((size_t)nc2 << 6) + fb;
        uint4 pa = *(const uint4*)pr;
        uint4 pb = *(const uint4*)(pr + 32);
        unsigned pw[8] = {pa.x, pa.y, pa.z, pa.w, pb.x, pb.y, pb.z, pb.w};
        bool he = d > 0;
        float vmean[16], vmax[16], vmin[16], vstd[16];
#pragma unroll
        for (int k = 0; k < 8; ++k) {
            float p0 = __uint_as_float(pw[k] << 16);
            float p1 = __uint_as_float(pw[k] & 0xFFFF0000u);
            int i0 = 2 * k, i1 = 2 * k + 1;
            float e0 = sum[i0] * inv, e1 = sum[i1] * inv;
            vstd[i0] = sqrtf(fmaxf(fmaf(-e0, e0, sq[i0] * inv), 0.f) + EPSV);
            vstd[i1] = sqrtf(fmaxf(fmaf(-e1, e1, sq[i1] * inv), 0.f) + EPSV);
            vmean[i0] = he ? p0 + e0 : 0.f;   vmean[i1] = he ? p1 + e1 : 0.f;
            vmax[i0] = he ? p0 + mx[i0] : 0.f; vmax[i1] = he ? p1 + mx[i1] : 0.f;
            vmin[i0] = he ? p0 + mn[i0] : 0.f; vmin[i1] = he ? p1 + mn[i1] : 0.f;
        }
        if (node < M) {
            u16* ob = AGGh + ((size_t)node << 8);
            *(uint4*)(ob + fb)            = pack8(vmean);
            *(uint4*)(ob + fb + 32)       = pack8(vmean + 8);
            *(uint4*)(ob + 64 + fb)       = pack8(vmax);
            *(uint4*)(ob + 64 + fb + 32)  = pack8(vmax + 8);
            *(uint4*)(ob + 128 + fb)      = pack8(vmin);
            *(uint4*)(ob + 128 + fb + 32) = pack8(vmin + 8);
            *(uint4*)(ob + 192 + fb)      = pack8(vstd);
            *(uint4*)(ob + 192 + fb + 32) = pack8(vstd + 8);
        }
    }

    f32x4 acc[2][6];  // [mt][cg + third*2]
#pragma unroll
    for (int mt = 0; mt < 2; ++mt)
#pragma unroll
        for (int tt = 0; tt < 6; ++tt) acc[mt][tt] = (f32x4){0.f, 0.f, 0.f, 0.f};

    // ---- Phase 1: k 0..63 over hIn (hi/lo split), cols 0:64 only ----
#pragma unroll
    for (int chunk = 0; chunk < 2; ++chunk) {
        {
            int r = t >> 2, seg = t & 3;
            int row = rows0 + r;
            float4 v0 = make_float4(0.f, 0.f, 0.f, 0.f), v1 = v0;
            if (row < M) {
                v0 = *(const float4*)&hIn[(size_t)row * 64 + chunk * 32 + seg * 8];
                v1 = *(const float4*)&hIn[(size_t)row * 64 + chunk * 32 + seg * 8 + 4];
            }
            s16x8 hv, lv;
            split8(v0, v1, hv, lv);
            *(s16x8*)&Ah[r * 40 + seg * 8] = hv;
            *(s16x8*)&Al[r * 40 + seg * 8] = lv;
        }
        if (t < 256) {
            int c = t >> 2, seg = t & 3;
            int k0g = chunk * 32;
            *(s16x8*)&Bh[c * 40 + seg * 8] = *(const s16x8*)&WT_hi[(size_t)c * 320 + k0g + seg * 8];
            *(s16x8*)&Bl[c * 40 + seg * 8] = *(const s16x8*)&WT_lo[(size_t)c * 320 + k0g + seg * 8];
        }
        __syncthreads();

        s16x8 ah[2], al[2];
#pragma unroll
        for (int mt = 0; mt < 2; ++mt) {
            int r = wm * 32 + mt * 16 + l16;
            ah[mt] = *(s16x8*)&Ah[r * 40 + quad * 8];
            al[mt] = *(s16x8*)&Al[r * 40 + quad * 8];
        }
#pragma unroll
        for (int cg = 0; cg < 2; ++cg) {
            int cc = wn * 32 + cg * 16 + l16;
            s16x8 bh = *(s16x8*)&Bh[cc * 40 + quad * 8];
            s16x8 bl = *(s16x8*)&Bl[cc * 40 + quad * 8];
#pragma unroll
            for (int mt = 0; mt < 2; ++mt) {
                acc[mt][cg] = MFMA(ah[mt], bh, acc[mt][cg]);
                acc[mt][cg] = MFMA(al[mt], bh, acc[mt][cg]);
                acc[mt][cg] = MFMA(ah[mt], bl, acc[mt][cg]);
            }
        }
        __syncthreads();
    }

    // ---- Phase 2: k 64..319 over AGGh (bf16 hi only), all 192 cols ----
    for (int chunk = 0; chunk < 8; ++chunk) {
        {
            int r = t >> 2, seg = t & 3;
            int row = rows0 + r;
            s16x8 v = (s16x8){0, 0, 0, 0, 0, 0, 0, 0};
            if (row < M) v = *(const s16x8*)&AGGh[(size_t)row * 256 + chunk * 32 + seg * 8];
            *(s16x8*)&Ah[r * 40 + seg * 8] = v;
        }
        {
            int k0g = 64 + chunk * 32;
#pragma unroll
            for (int it = 0; it < 2; ++it) {
                int task = it * 512 + t;
                if (task < 768) {
                    int c = task >> 2, seg = task & 3;
                    *(s16x8*)&Bh[c * 40 + seg * 8] = *(const s16x8*)&WT_hi[(size_t)c * 320 + k0g + seg * 8];
                    *(s16x8*)&Bl[c * 40 + seg * 8] = *(const s16x8*)&WT_lo[(size_t)c * 320 + k0g + seg * 8];
                }
            }
        }
        __syncthreads();

        s16x8 ah[2];
#pragma unroll
        for (int mt = 0; mt < 2; ++mt) {
            int r = wm * 32 + mt * 16 + l16;
            ah[mt] = *(s16x8*)&Ah[r * 40 + quad * 8];
        }
#pragma unroll
        for (int tt = 0; tt < 6; ++tt) {
            int cc = wn * 32 + (tt & 1) * 16 + (tt >> 1) * 64 + l16;
            s16x8 bh = *(s16x8*)&Bh[cc * 40 + quad * 8];
            s16x8 bl = *(s16x8*)&Bl[cc * 40 + quad * 8];
#pragma unroll
            for (int mt = 0; mt < 2; ++mt) {
                acc[mt][tt] = MFMA(ah[mt], bh, acc[mt][tt]);
                acc[mt][tt] = MFMA(ah[mt], bl, acc[mt][tt]);
            }
        }
        __syncthreads();
    }

    // ---- Epilogue: combine thirds (amp/att inline), residual + bias ----
    float hv[2][2][4];
    float avg = *lsum / (float)M;
#pragma unroll
    for (int mt = 0; mt < 2; ++mt)
#pragma unroll
        for (int r = 0; r < 4; ++r) {
            int row = rows0 + wm * 32 + mt * 16 + quad * 4 + r;
            float am = 1.f, at = 1.f, hin0 = 0.f, hin1 = 0.f;
            if (row < M) {
                float dc = fmaxf((float)degp[row], 1.f);
                float ld = logf(dc + 1.f);
                am = ld / avg;
                at = avg / ld;
                hin0 = hIn[(size_t)row * 64 + wn * 32 + l16];
                hin1 = hIn[(size_t)row * 64 + wn * 32 + 16 + l16];
            }
#pragma unroll
            for (int cg = 0; cg < 2; ++cg) {
                int col = wn * 32 + cg * 16 + l16;
                float v = acc[mt][cg][r] + am * acc[mt][cg + 2][r] + at * acc[mt][cg + 4][r]
                        + (cg == 0 ? hin0 : hin1) + bpp[col];
                hv[mt][cg][r] = v;
                if (row < M) hOut[(size_t)row * 64 + col] = v;
            }
        }

    // ---- Phase C (doNext): gemm1(l+1) from in-register h' ----
    if (doNext) {
        f32x4 acc2[2][4];
#pragma unroll
        for (int mt = 0; mt < 2; ++mt)
#pragma unroll
            for (int tt = 0; tt < 4; ++tt) acc2[mt][tt] = (f32x4){0.f, 0.f, 0.f, 0.f};

#pragma unroll
        for (int chunk = 0; chunk < 2; ++chunk) {
            {
                int c = t >> 2, seg = t & 3;
                *(s16x8*)&Bh[c * 40 + seg * 8] = *(const s16x8*)&WpN_hi[(size_t)c * 64 + chunk * 32 + seg * 8];
                *(s16x8*)&Bl[c * 40 + seg * 8] = *(const s16x8*)&WpN_lo[(size_t)c * 64 + chunk * 32 + seg * 8];
            }
            if (wn == chunk) {
#pragma unroll
                for (int mt = 0; mt < 2; ++mt)
#pragma unroll
                    for (int cg = 0; cg < 2; ++cg) {
                        int lc = cg * 16 + l16;
#pragma unroll
                        for (int r = 0; r < 4; ++r) {
                            int rl = wm * 32 + mt * 16 + quad * 4 + r;
                            float v = hv[mt][cg][r];
                            u16 hi = f2bf(v);
                            Ah[rl * 40 + lc] = hi;
                            Al[rl * 40 + lc] = f2bf(v - bf2f(hi));
                        }
                    }
            }
            __syncthreads();

            s16x8 ah[2], al[2];
#pragma unroll
            for (int mt = 0; mt < 2; ++mt) {
                int r = wm * 32 + mt * 16 + l16;
                ah[mt] = *(s16x8*)&Ah[r * 40 + quad * 8];
                al[mt] = *(s16x8*)&Al[r * 40 + quad * 8];
            }
#pragma unroll
            for (int tt = 0; tt < 4; ++tt) {
                int cc = wn * 64 + tt * 16 + l16;
                s16x8 bh = *(s16x8*)&Bh[cc * 40 + quad * 8];
                s16x8 bl = *(s16x8*)&Bl[cc * 40 + quad * 8];
#pragma unroll
                for (int mt = 0; mt < 2; ++mt) {
                    acc2[mt][tt] = MFMA(ah[mt], bh, acc2[mt][tt]);
                    acc2[mt][tt] = MFMA(ah[mt], bl, acc2[mt][tt]);
                    if (wn == 0) acc2[mt][tt] = MFMA(al[mt], bh, acc2[mt][tt]);
                }
            }
            __syncthreads();
        }

#pragma unroll
        for (int mt = 0; mt < 2; ++mt)
#pragma unroll
            for (int tt = 0; tt < 4; ++tt) {
                int col = wn * 64 + tt * 16 + l16;
#pragma unroll
                for (int r = 0; r < 4; ++r) {
                    int row = rows0 + wm * 32 + mt * 16 + quad * 4 + r;
                    if (row >= M) continue;
                    float v = acc2[mt][tt][r];
                    if (col < 64) PhN[(size_t)row * 64 + col] = f2bf(v + pre_bN[col]);
                    else          QhN[(size_t)row * 64 + (col - 64)] = f2bf(v);
                }
            }
    }
}

// ---------------- launch ----------------

extern "C" void kernel_launch(void* const* d_in, const int* in_sizes, int n_in,
                              void* d_out, int out_size, void* d_ws, size_t ws_size,
                              hipStream_t stream) {
    const float* x      = (const float*)d_in[0];
    const int*   ei     = (const int*)d_in[1];
    const float* pre_w  = (const float*)d_in[2];
    const float* pre_b  = (const float*)d_in[3];
    const float* post_w = (const float*)d_in[4];
    const float* post_b = (const float*)d_in[5];
    const float* lin_w  = (const float*)d_in[6];
    const float* lin_b  = (const float*)d_in[7];

    const int N = in_sizes[0] / 64;
    const int E = in_sizes[1] / 2;
    const int L = in_sizes[2] / (128 * 64);

    const int* srcIdx = ei;
    const int* dstIdx = ei + E;

    char* ws = (char*)d_ws;
    size_t off = 0;
    auto alloc = [&](size_t bytes) {
        void* p = ws + off;
        off += (bytes + 255) & ~(size_t)255;
        return p;
    };
    int*      deg        = (int*)alloc((size_t)N * 4);
    int*      offs       = (int*)alloc((size_t)(N + 1) * 4);
    u16*      srcSorted  = (u16*)alloc((size_t)NBP * CAPS * 2);
    unsigned* edgeTmp    = (unsigned*)alloc((size_t)NBP * CAP * 4);
    int*      bucketCur  = (int*)alloc(NBP * 4);
    float*    lsum       = (float*)alloc(256);
    u16*      WpT_hi     = (u16*)alloc((size_t)L * 128 * 64 * 2);
    u16*      WpT_lo     = (u16*)alloc((size_t)L * 128 * 64 * 2);
    u16*      WT_hi      = (u16*)alloc((size_t)L * 192 * 320 * 2);
    u16*      WT_lo      = (u16*)alloc((size_t)L * 192 * 320 * 2);
    float*    bpp        = (float*)alloc((size_t)L * 64 * 4);
    u16*      Ph0        = (u16*)alloc((size_t)N * 64 * 2);
    u16*      Qh0        = (u16*)alloc((size_t)N * 64 * 2);
    u16*      Ph1        = (u16*)alloc((size_t)N * 64 * 2);
    u16*      Qh1        = (u16*)alloc((size_t)N * 64 * 2);
    u16*      AGGh       = (u16*)alloc((size_t)N * 256 * 2);
    float*    hA         = (float*)alloc((size_t)N * 64 * 4);
    float*    hB         = (float*)alloc((size_t)N * 64 * 4);
    (void)ws_size;

    u16* PhB[2] = {Ph0, Ph1};
    u16* QhB[2] = {Qh0, Qh1};

    int NB = (N + 255) >> 8;
    int NB1 = (E + EPB3 - 1) / EPB3;
    int gblk = (N + 63) / 64;
    int gblk2 = (N + 127) / 128;

    hipMemsetAsync(bucketCur, 0, NBP * 4, stream);
    hipMemsetAsync(lsum, 0, 4, stream);

    k_pre1<<<NB1 + 449 * L, 512, 0, stream>>>(
        srcIdx, dstIdx, E, bucketCur, edgeTmp,
        pre_w, post_w, post_b, lin_w, lin_b,
        WpT_hi, WpT_lo, WT_hi, WT_lo, bpp, NB1);

    k_pre2<<<NB + gblk, 512, 0, stream>>>(
        edgeTmp, bucketCur, deg, offs, lsum, srcSorted,
        x, WpT_hi, WpT_lo, pre_b, PhB[0], QhB[0], N, E, NB);

    const float* hIn = x;
    float* hbuf[2] = {hA, hB};
    for (int l = 0; l < L; ++l) {
        float* hOut = (l == L - 1) ? (float*)d_out : hbuf[l & 1];
        int dn = (l < L - 1) ? 1 : 0;
        int ln = dn ? (l + 1) : 0;
        k_layer<<<gblk2, 512, 0, stream>>>(
            hIn, PhB[l & 1], QhB[l & 1], offs, deg, srcSorted, AGGh,
            WT_hi + (size_t)l * 192 * 320,
            WT_lo + (size_t)l * 192 * 320,
            bpp + (size_t)l * 64,
            lsum, hOut, dn,
            WpT_hi + (size_t)ln * 128 * 64,
            WpT_lo + (size_t)ln * 128 * 64,
            pre_b + (size_t)ln * 64,
            PhB[(l + 1) & 1], QhB[(l + 1) & 1], N);
        hIn = hOut;
    }
}

// Round 5
// 268.268 us; speedup vs baseline: 1.1396x; 1.1396x over previous
//
#include <hip/hip_runtime.h>
#include <math.h>

#define EPSV 1e-5f
#define EPB3 4096  // edges per bucket-pass block (196 blocks, proven config)
#define NBP 256    // buckets of 256 nodes (N <= 65536; src packed in 16 bits)
#define CAP 6144   // per-bucket edgeTmp slab capacity (mean ~4081, +32 sigma)
#define CAPS (CAP + 768)  // padded sorted-slab capacity (pad <=3 per node)

typedef short s16x8 __attribute__((ext_vector_type(8)));
typedef float f32x4 __attribute__((ext_vector_type(4)));
typedef unsigned short u16;
typedef unsigned short u16x4 __attribute__((ext_vector_type(4)));

#define MFMA(a, b, c) __builtin_amdgcn_mfma_f32_16x16x32_bf16(a, b, c, 0, 0, 0)

__device__ inline u16 f2bf(float f) {
    unsigned u = __float_as_uint(f);
    return (u16)((u + 0x7FFF + ((u >> 16) & 1)) >> 16);
}
__device__ inline float bf2f(u16 h) { return __uint_as_float(((unsigned)h) << 16); }

__device__ inline void split8(const float4& a, const float4& b, s16x8& hv, s16x8& lv) {
    float f[8] = {a.x, a.y, a.z, a.w, b.x, b.y, b.z, b.w};
#pragma unroll
    for (int i = 0; i < 8; ++i) {
        u16 h = f2bf(f[i]);
        hv[i] = (short)h;
        lv[i] = (short)f2bf(f[i] - bf2f(h));
    }
}

// ---------------- pre1: bucket partition + weight prep (merged) ----------------
// blocks [0, NB1): bucket3 body. blocks [NB1, NB1+449*L): wprep body.
__global__ __launch_bounds__(512) void k_pre1(
    const int* __restrict__ src, const int* __restrict__ dst, int E,
    int* __restrict__ bucketCursor, unsigned* __restrict__ edgeTmp,
    const float* __restrict__ pre_w, const float* __restrict__ post_w,
    const float* __restrict__ post_b, const float* __restrict__ lin_w,
    const float* __restrict__ lin_b, u16* __restrict__ WpT_hi,
    u16* __restrict__ WpT_lo, u16* __restrict__ WT_hi, u16* __restrict__ WT_lo,
    float* __restrict__ bpp, int NB1) {
    __shared__ int cnt[NBP], loff[NBP], lpos[NBP], gbase[NBP], sbuf[NBP];
    __shared__ unsigned stage[EPB3];
    int t = threadIdx.x;
    if ((int)blockIdx.x < NB1) {
        // ---- bucket3 body ----
        int base = blockIdx.x * EPB3;
        int cntE = min(EPB3, E - base);
        if (t < NBP) cnt[t] = 0;
        __syncthreads();
        unsigned ed[8];
#pragma unroll
        for (int j = 0; j < 8; ++j) {
            int idx = j * 512 + t;
            if (idx < cntE) {
                int e = base + idx;
                unsigned s = (unsigned)src[e];
                unsigned d = (unsigned)dst[e];
                ed[j] = ((d >> 8) << 24) | ((d & 255u) << 16) | s;
                atomicAdd(&cnt[d >> 8], 1);
            } else ed[j] = 0xFFFFFFFFu;
        }
        __syncthreads();
        if (t < NBP) sbuf[t] = cnt[t];
        __syncthreads();
        for (int o = 1; o < NBP; o <<= 1) {
            int v = 0;
            if (t < NBP && t >= o) v = sbuf[t - o];
            __syncthreads();
            if (t < NBP) sbuf[t] += v;
            __syncthreads();
        }
        if (t < NBP) {
            loff[t] = sbuf[t] - cnt[t];
            lpos[t] = sbuf[t] - cnt[t];
            gbase[t] = (cnt[t] > 0) ? atomicAdd(&bucketCursor[t], cnt[t]) : 0;
        }
        __syncthreads();
#pragma unroll
        for (int j = 0; j < 8; ++j) {
            if (ed[j] != 0xFFFFFFFFu) {
                int b = ed[j] >> 24;
                int p = atomicAdd(&lpos[b], 1);
                stage[p] = ed[j];
            }
        }
        __syncthreads();
        for (int i = t; i < cntE; i += 512) {
            unsigned pr = stage[i];
            int b = pr >> 24;
            int pos = gbase[b] + (i - loff[b]);
            if (pos < CAP) edgeTmp[(size_t)b * CAP + pos] = pr;
        }
        return;
    }
    // ---- wprep body ----
    int wq = blockIdx.x - NB1;
    int l = wq / 449;
    int bx = wq - l * 449;
    if (bx < 320) {
        if (t < 192) {
            int k = bx, j = t;
            int third = j >> 6, c = j & 63;
            float out = 0.f;
            int r = -1;
            if (k < 64) r = (third == 0) ? k : -1;
            else        r = 64 + third * 256 + (k - 64);
            if (r >= 0) {
                const float* pw = post_w + (size_t)(l * 832 + r) * 64;
                const float* lw = lin_w + (size_t)l * 64 * 64;
                float s = 0.f;
                for (int kk = 0; kk < 64; ++kk) s += pw[kk] * lw[kk * 64 + c];
                out = s;
            }
            u16 h = f2bf(out);
            size_t o = ((size_t)l * 192 + j) * 320 + k;
            WT_hi[o] = h;
            WT_lo[o] = f2bf(out - bf2f(h));
        }
    } else if (bx < 448) {
        if (t < 64) {
            int c = bx - 320, k = t;
            float v = pre_w[(size_t)l * 8192 + (size_t)(k + (c >= 64 ? 64 : 0)) * 64 + (c & 63)];
            u16 h = f2bf(v);
            size_t o = ((size_t)l * 128 + c) * 64 + k;
            WpT_hi[o] = h;
            WpT_lo[o] = f2bf(v - bf2f(h));
        }
    } else {
        if (t < 64) {
            int c = t;
            const float* pb = post_b + l * 64;
            const float* lw = lin_w + (size_t)l * 64 * 64;
            float s = lin_b[l * 64 + c];
            for (int k = 0; k < 64; ++k) s += pb[k] * lw[k * 64 + c];
            bpp[l * 64 + c] = s;
        }
    }
}

// ---------------- pre2: counting-sort + layer-0 gemm1 (merged) ----------------
// blocks [0, NB): csort body. blocks [NB, NB+gblk): gemm1 body (t<256, one barrier).
__global__ __launch_bounds__(512) void k_pre2(
    const unsigned* __restrict__ edgeTmp, const int* __restrict__ bucketCur,
    int* __restrict__ deg, int* __restrict__ offs, float* __restrict__ lsum,
    u16* __restrict__ srcSorted,
    const float* __restrict__ x, const u16* __restrict__ WpT_hi,
    const u16* __restrict__ WpT_lo, const float* __restrict__ pre_b,
    u16* __restrict__ Ph, u16* __restrict__ Qh,
    int N, int E, int NB) {
    __shared__ __align__(16) char smem[55296];
    int t = threadIdx.x;
    if ((int)blockIdx.x < NB) {
        // ---- csort body: per-bucket padded slabs ----
        int* scnt = (int*)smem;
        int* sbuf = (int*)(smem + 1024);
        int* lcur = (int*)(smem + 2048);
        int* lofs = (int*)(smem + 3072);
        float* fred = (float*)(smem + 4096);
        u16* stageSrc = (u16*)(smem + 5120);
        int* cntPs = (int*)(smem + 5120 + CAPS * 2);
        int b = blockIdx.x;
        int n0 = b << 8;
        int nodes = min(256, N - n0);
        if (t < NBP) { lcur[t] = 0; scnt[t] = 0; }
        __syncthreads();
        int cnt = min(bucketCur[b], CAP);
        const unsigned* ebase = edgeTmp + (size_t)b * CAP;
        for (int i = t; i < cnt; i += 512) atomicAdd(&lcur[(ebase[i] >> 16) & 255], 1);
        __syncthreads();
        float ls = 0.f;
        int d = 0, dP = 0;
        if (t < nodes) {
            d = lcur[t];
            deg[n0 + t] = d;
            ls = logf(fmaxf((float)d, 1.f) + 1.f);
            dP = (d + 3) & ~3;
        }
        if (t < 256) fred[t] = ls;
        if (t < NBP) sbuf[t] = dP;
        __syncthreads();
        for (int o = 1; o < NBP; o <<= 1) {
            int v = 0;
            if (t < NBP && t >= o) v = sbuf[t - o];
            __syncthreads();
            if (t < NBP) sbuf[t] += v;
            __syncthreads();
        }
        if (t < NBP) lofs[t] = sbuf[t] - dP;
        if (t < nodes) offs[n0 + t] = b * CAPS + (sbuf[t] - dP);
        if (t == NBP - 1) *cntPs = sbuf[t];
        __syncthreads();
        for (int o = 128; o > 0; o >>= 1) {
            if (t < o) fred[t] += fred[t + o];
            __syncthreads();
        }
        if (t == 0) atomicAdd(lsum, fred[0]);
        for (int i = t; i < cnt; i += 512) {
            unsigned p = ebase[i];
            int dl = (p >> 16) & 255;
            int r = atomicAdd(&scnt[dl], 1);
            stageSrc[lofs[dl] + r] = (u16)(p & 0xFFFFu);
        }
        __syncthreads();
        if (t < nodes && (d & 3)) {
            int lp = lofs[t];
            u16 lastv = stageSrc[lp + d - 1];
            for (int k = d; k < dP; ++k) stageSrc[lp + k] = lastv;
        }
        __syncthreads();
        int cntP = *cntPs;
        for (int i = t; i < cntP; i += 512) srcSorted[(size_t)b * CAPS + i] = stageSrc[i];
        return;
    }
    // ---- gemm1 body: 64 rows, threads 0..255, ONE hoisted barrier ----
    u16* Ah = (u16*)smem;            // 64*72 u16 = 9216 B
    u16* Al = (u16*)(smem + 9216);
    u16* Bh = (u16*)(smem + 18432);  // 128*72 u16 = 18432 B
    u16* Bl = (u16*)(smem + 36864);
    int rows0 = ((int)blockIdx.x - NB) * 64;
    int wid = t >> 6, lane = t & 63;
    int quad = lane >> 4, l16 = lane & 15;
    int wm = wid & 1, wn = wid >> 1;
    if (t < 256) {
#pragma unroll
        for (int it = 0; it < 2; ++it) {
            int task = it * 256 + t;
            int r = task >> 3, seg = task & 7;
            int row = rows0 + r;
            float4 v0 = make_float4(0.f, 0.f, 0.f, 0.f), v1 = v0;
            if (row < N) {
                v0 = *(const float4*)&x[(size_t)row * 64 + seg * 8];
                v1 = *(const float4*)&x[(size_t)row * 64 + seg * 8 + 4];
            }
            s16x8 hv, lv;
            split8(v0, v1, hv, lv);
            *(s16x8*)&Ah[r * 72 + seg * 8] = hv;
            *(s16x8*)&Al[r * 72 + seg * 8] = lv;
        }
#pragma unroll
        for (int it = 0; it < 4; ++it) {
            int task = it * 256 + t;
            int c = task >> 3, seg = task & 7;
            *(s16x8*)&Bh[c * 72 + seg * 8] = *(const s16x8*)&WpT_hi[(size_t)c * 64 + seg * 8];
            *(s16x8*)&Bl[c * 72 + seg * 8] = *(const s16x8*)&WpT_lo[(size_t)c * 64 + seg * 8];
        }
    }
    __syncthreads();
    if (t < 256) {
        f32x4 acc[2][4];
#pragma unroll
        for (int mt = 0; mt < 2; ++mt)
#pragma unroll
            for (int tt = 0; tt < 4; ++tt) acc[mt][tt] = (f32x4){0.f, 0.f, 0.f, 0.f};
#pragma unroll
        for (int c = 0; c < 2; ++c) {
            s16x8 ah[2], al[2];
#pragma unroll
            for (int mt = 0; mt < 2; ++mt) {
                int r = wm * 32 + mt * 16 + l16;
                ah[mt] = *(s16x8*)&Ah[r * 72 + c * 32 + quad * 8];
                al[mt] = *(s16x8*)&Al[r * 72 + c * 32 + quad * 8];
            }
#pragma unroll
            for (int tt = 0; tt < 4; ++tt) {
                int cc = wn * 64 + tt * 16 + l16;
                s16x8 bh = *(s16x8*)&Bh[cc * 72 + c * 32 + quad * 8];
                s16x8 bl = *(s16x8*)&Bl[cc * 72 + c * 32 + quad * 8];
#pragma unroll
                for (int mt = 0; mt < 2; ++mt) {
                    acc[mt][tt] = MFMA(ah[mt], bh, acc[mt][tt]);
                    acc[mt][tt] = MFMA(ah[mt], bl, acc[mt][tt]);
                    if (wn == 0) acc[mt][tt] = MFMA(al[mt], bh, acc[mt][tt]);
                }
            }
        }
#pragma unroll
        for (int mt = 0; mt < 2; ++mt)
#pragma unroll
            for (int tt = 0; tt < 4; ++tt) {
                int col = wn * 64 + tt * 16 + l16;
#pragma unroll
                for (int r = 0; r < 4; ++r) {
                    int row = rows0 + wm * 32 + mt * 16 + quad * 4 + r;
                    if (row >= N) continue;
                    float v = acc[mt][tt][r];
                    if (col < 64) Ph[(size_t)row * 64 + col] = f2bf(v + pre_b[col]);
                    else          Qh[(size_t)row * 64 + (col - 64)] = f2bf(v);
                }
            }
    }
}

// ---------------- per-layer kernels (round-3 proven) ----------------

// aggregation v4: one wave = 4 nodes; 16-lane group g owns a node (4 feats/lane).
// Padded CSR (deg rounded up to x4, dup last edge) -> branch-free body: one
// uint2 load fetches 4 edge indices, 4 independent uint2 gathers, 4x ACC4.
// Pad duplicates are exact no-ops for max/min; sum/sq corrected at the end.
__global__ __launch_bounds__(256) void k_agg(const u16* __restrict__ Ph,
                                             const u16* __restrict__ Qh,
                                             const int* __restrict__ offs,
                                             const int* __restrict__ degp,
                                             const u16* __restrict__ ss,
                                             u16* __restrict__ AGGh, int N) {
    int w = threadIdx.x >> 6, lane = threadIdx.x & 63;
    int g = lane >> 4;              // node sub-slot 0..3
    int f4b = (lane & 15) << 3;     // byte offset of this lane's 4 features
    int node = blockIdx.x * 16 + w * 4 + g;
    int nc = min(node, N - 1);
    int beg = offs[nc];
    int d = (node < N) ? degp[nc] : 0;
    int dP = (d + 3) & ~3;
    int end = beg + dP;
    int mdP = dP;
    mdP = max(mdP, __shfl_xor(mdP, 16));
    mdP = max(mdP, __shfl_xor(mdP, 32));
    int trips = mdP >> 2;

    float sum0 = 0.f, sum1 = 0.f, sum2 = 0.f, sum3 = 0.f;
    float sq0 = 0.f, sq1 = 0.f, sq2 = 0.f, sq3 = 0.f;
    float mx0 = -3.4e38f, mx1 = -3.4e38f, mx2 = -3.4e38f, mx3 = -3.4e38f;
    float mn0 = 3.4e38f, mn1 = 3.4e38f, mn2 = 3.4e38f, mn3 = 3.4e38f;

    const char* qbase = (const char*)Qh;

#define ACC4(LO, HI)                                                        \
    {                                                                       \
        float q0 = __uint_as_float((LO) << 16);                             \
        float q1 = __uint_as_float((LO) & 0xFFFF0000u);                     \
        float q2 = __uint_as_float((HI) << 16);                             \
        float q3 = __uint_as_float((HI) & 0xFFFF0000u);                     \
        sum0 += q0; sq0 = fmaf(q0, q0, sq0);                                \
        mx0 = fmaxf(mx0, q0); mn0 = fminf(mn0, q0);                         \
        sum1 += q1; sq1 = fmaf(q1, q1, sq1);                                \
        mx1 = fmaxf(mx1, q1); mn1 = fminf(mn1, q1);                         \
        sum2 += q2; sq2 = fmaf(q2, q2, sq2);                                \
        mx2 = fmaxf(mx2, q2); mn2 = fminf(mn2, q2);                         \
        sum3 += q3; sq3 = fmaf(q3, q3, sq3);                                \
        mx3 = fmaxf(mx3, q3); mn3 = fminf(mn3, q3);                         \
    }

    int e = beg;
    for (int it = 0; it < trips; ++it, e += 4) {
        if (e < end) {
            uint2 sw = *(const uint2*)(ss + e);  // 4 packed src ids
            unsigned a0 = ((sw.x & 0xFFFFu) << 7) | (unsigned)f4b;
            unsigned a1 = ((sw.x >> 16) << 7) | (unsigned)f4b;
            unsigned a2 = ((sw.y & 0xFFFFu) << 7) | (unsigned)f4b;
            unsigned a3 = ((sw.y >> 16) << 7) | (unsigned)f4b;
            uint2 qa = *(const uint2*)(qbase + a0);
            uint2 qb = *(const uint2*)(qbase + a1);
            uint2 qc = *(const uint2*)(qbase + a2);
            uint2 qd = *(const uint2*)(qbase + a3);
            ACC4(qa.x, qa.y);
            ACC4(qb.x, qb.y);
            ACC4(qc.x, qc.y);
            ACC4(qd.x, qd.y);
        }
    }
#undef ACC4

    if (d & 3) {
        unsigned sl = ss[beg + d - 1];
        uint2 ql = *(const uint2*)(qbase + ((sl << 7) | (unsigned)f4b));
        float padf = (float)(dP - d);
        float qL0 = __uint_as_float(ql.x << 16);
        float qL1 = __uint_as_float(ql.x & 0xFFFF0000u);
        float qL2 = __uint_as_float(ql.y << 16);
        float qL3 = __uint_as_float(ql.y & 0xFFFF0000u);
        float t0 = padf * qL0, t1 = padf * qL1, t2 = padf * qL2, t3 = padf * qL3;
        sum0 -= t0; sq0 = fmaf(-t0, qL0, sq0);
        sum1 -= t1; sq1 = fmaf(-t1, qL1, sq1);
        sum2 -= t2; sq2 = fmaf(-t2, qL2, sq2);
        sum3 -= t3; sq3 = fmaf(-t3, qL3, sq3);
    }

    float dc = fmaxf((float)d, 1.f);
    float inv = 1.0f / dc;
    float e0 = sum0 * inv, e1 = sum1 * inv, e2 = sum2 * inv, e3 = sum3 * inv;
    float sd0 = sqrtf(fmaxf(fmaf(-e0, e0, sq0 * inv), 0.f) + EPSV);
    float sd1 = sqrtf(fmaxf(fmaf(-e1, e1, sq1 * inv), 0.f) + EPSV);
    float sd2 = sqrtf(fmaxf(fmaf(-e2, e2, sq2 * inv), 0.f) + EPSV);
    float sd3 = sqrtf(fmaxf(fmaf(-e3, e3, sq3 * inv), 0.f) + EPSV);

    uint2 pw = *(const uint2*)((const char*)Ph + (((unsigned)nc << 7) | (unsigned)f4b));
    float p0 = __uint_as_float(pw.x << 16), p1 = __uint_as_float(pw.x & 0xFFFF0000u);
    float p2 = __uint_as_float(pw.y << 16), p3 = __uint_as_float(pw.y & 0xFFFF0000u);

    bool he = d > 0;
    float m0 = he ? p0 + e0 : 0.f, m1 = he ? p1 + e1 : 0.f;
    float m2 = he ? p2 + e2 : 0.f, m3 = he ? p3 + e3 : 0.f;
    float X0 = he ? p0 + mx0 : 0.f, X1 = he ? p1 + mx1 : 0.f;
    float X2 = he ? p2 + mx2 : 0.f, X3 = he ? p3 + mx3 : 0.f;
    float n0 = he ? p0 + mn0 : 0.f, n1 = he ? p1 + mn1 : 0.f;
    float n2 = he ? p2 + mn2 : 0.f, n3 = he ? p3 + mn3 : 0.f;

    if (node < N) {
        u16* out = (u16*)((char*)AGGh + (((unsigned)node << 9) | (unsigned)f4b));
        *(u16x4*)(out)       = (u16x4){f2bf(m0), f2bf(m1), f2bf(m2), f2bf(m3)};
        *(u16x4*)(out + 64)  = (u16x4){f2bf(X0), f2bf(X1), f2bf(X2), f2bf(X3)};
        *(u16x4*)(out + 128) = (u16x4){f2bf(n0), f2bf(n1), f2bf(n2), f2bf(n3)};
        *(u16x4*)(out + 192) = (u16x4){f2bf(sd0), f2bf(sd1), f2bf(sd2), f2bf(sd3)};
    }
}

// gemm2: 128-row blocks, 512 threads. Computes h' and (doNext) fuses
// gemm1(l+1) as phase C from in-register h' (same 51.2KB LDS reused).
__global__ __launch_bounds__(512) void k_gemm2(const float* __restrict__ hIn,
                                               const u16* __restrict__ AGGh,
                                               const u16* __restrict__ WT_hi,
                                               const u16* __restrict__ WT_lo,
                                               const float* __restrict__ bpp,
                                               const int* __restrict__ degp,
                                               const float* __restrict__ lsum,
                                               float* __restrict__ hOut,
                                               int doNext,
                                               const u16* __restrict__ WpN_hi,
                                               const u16* __restrict__ WpN_lo,
                                               const float* __restrict__ pre_bN,
                                               u16* __restrict__ PhN,
                                               u16* __restrict__ QhN, int M) {
    __shared__ u16 Ah[128 * 40], Al[128 * 40];  // [row][k-chunk 32], pitch 40
    __shared__ u16 Bh[192 * 40], Bl[192 * 40];  // [col][k-chunk 32], pitch 40
    int t = threadIdx.x, wid = t >> 6, lane = t & 63;
    int rows0 = blockIdx.x * 128;
    int quad = lane >> 4, l16 = lane & 15;
    int wm = wid & 3, wn = wid >> 2;

    f32x4 acc[2][6];  // [mt][cg + third*2]
#pragma unroll
    for (int mt = 0; mt < 2; ++mt)
#pragma unroll
        for (int tt = 0; tt < 6; ++tt) acc[mt][tt] = (f32x4){0.f, 0.f, 0.f, 0.f};

    // ---- Phase 1: k 0..63 over hIn (hi/lo split), cols 0:64 only ----
#pragma unroll
    for (int chunk = 0; chunk < 2; ++chunk) {
        {
            int r = t >> 2, seg = t & 3;
            int row = rows0 + r;
            float4 v0 = make_float4(0.f, 0.f, 0.f, 0.f), v1 = v0;
            if (row < M) {
                v0 = *(const float4*)&hIn[(size_t)row * 64 + chunk * 32 + seg * 8];
                v1 = *(const float4*)&hIn[(size_t)row * 64 + chunk * 32 + seg * 8 + 4];
            }
            s16x8 hv, lv;
            split8(v0, v1, hv, lv);
            *(s16x8*)&Ah[r * 40 + seg * 8] = hv;
            *(s16x8*)&Al[r * 40 + seg * 8] = lv;
        }
        if (t < 256) {
            int c = t >> 2, seg = t & 3;
            int k0g = chunk * 32;
            *(s16x8*)&Bh[c * 40 + seg * 8] = *(const s16x8*)&WT_hi[(size_t)c * 320 + k0g + seg * 8];
            *(s16x8*)&Bl[c * 40 + seg * 8] = *(const s16x8*)&WT_lo[(size_t)c * 320 + k0g + seg * 8];
        }
        __syncthreads();

        s16x8 ah[2], al[2];
#pragma unroll
        for (int mt = 0; mt < 2; ++mt) {
            int r = wm * 32 + mt * 16 + l16;
            ah[mt] = *(s16x8*)&Ah[r * 40 + quad * 8];
            al[mt] = *(s16x8*)&Al[r * 40 + quad * 8];
        }
#pragma unroll
        for (int cg = 0; cg < 2; ++cg) {
            int cc = wn * 32 + cg * 16 + l16;
            s16x8 bh = *(s16x8*)&Bh[cc * 40 + quad * 8];
            s16x8 bl = *(s16x8*)&Bl[cc * 40 + quad * 8];
#pragma unroll
            for (int mt = 0; mt < 2; ++mt) {
                acc[mt][cg] = MFMA(ah[mt], bh, acc[mt][cg]);
                acc[mt][cg] = MFMA(al[mt], bh, acc[mt][cg]);
                acc[mt][cg] = MFMA(ah[mt], bl, acc[mt][cg]);
            }
        }
        __syncthreads();
    }

    // ---- Phase 2: k 64..319 over AGGh (bf16 hi only), all 192 cols ----
    for (int chunk = 0; chunk < 8; ++chunk) {
        {
            int r = t >> 2, seg = t & 3;
            int row = rows0 + r;
            s16x8 v = (s16x8){0, 0, 0, 0, 0, 0, 0, 0};
            if (row < M) v = *(const s16x8*)&AGGh[(size_t)row * 256 + chunk * 32 + seg * 8];
            *(s16x8*)&Ah[r * 40 + seg * 8] = v;
        }
        {
            int k0g = 64 + chunk * 32;
#pragma unroll
            for (int it = 0; it < 2; ++it) {
                int task = it * 512 + t;
                if (task < 768) {
                    int c = task >> 2, seg = task & 3;
                    *(s16x8*)&Bh[c * 40 + seg * 8] = *(const s16x8*)&WT_hi[(size_t)c * 320 + k0g + seg * 8];
                    *(s16x8*)&Bl[c * 40 + seg * 8] = *(const s16x8*)&WT_lo[(size_t)c * 320 + k0g + seg * 8];
                }
            }
        }
        __syncthreads();

        s16x8 ah[2];
#pragma unroll
        for (int mt = 0; mt < 2; ++mt) {
            int r = wm * 32 + mt * 16 + l16;
            ah[mt] = *(s16x8*)&Ah[r * 40 + quad * 8];
        }
#pragma unroll
        for (int tt = 0; tt < 6; ++tt) {
            int cc = wn * 32 + (tt & 1) * 16 + (tt >> 1) * 64 + l16;
            s16x8 bh = *(s16x8*)&Bh[cc * 40 + quad * 8];
            s16x8 bl = *(s16x8*)&Bl[cc * 40 + quad * 8];
#pragma unroll
            for (int mt = 0; mt < 2; ++mt) {
                acc[mt][tt] = MFMA(ah[mt], bh, acc[mt][tt]);
                acc[mt][tt] = MFMA(ah[mt], bl, acc[mt][tt]);
            }
        }
        __syncthreads();
    }

    // ---- Epilogue: combine thirds (amp/att inline), residual + bias ----
    float hv[2][2][4];
    float avg = *lsum / (float)M;
#pragma unroll
    for (int mt = 0; mt < 2; ++mt)
#pragma unroll
        for (int r = 0; r < 4; ++r) {
            int row = rows0 + wm * 32 + mt * 16 + quad * 4 + r;
            float am = 1.f, at = 1.f, hin0 = 0.f, hin1 = 0.f;
            if (row < M) {
                float dc = fmaxf((float)degp[row], 1.f);
                float ld = logf(dc + 1.f);
                am = ld / avg;
                at = avg / ld;
                hin0 = hIn[(size_t)row * 64 + wn * 32 + l16];
                hin1 = hIn[(size_t)row * 64 + wn * 32 + 16 + l16];
            }
#pragma unroll
            for (int cg = 0; cg < 2; ++cg) {
                int col = wn * 32 + cg * 16 + l16;
                float v = acc[mt][cg][r] + am * acc[mt][cg + 2][r] + at * acc[mt][cg + 4][r]
                        + (cg == 0 ? hin0 : hin1) + bpp[col];
                hv[mt][cg][r] = v;
                if (row < M) hOut[(size_t)row * 64 + col] = v;
            }
        }

    // ---- Phase C (doNext): gemm1(l+1) from in-register h' ----
    if (doNext) {
        f32x4 acc2[2][4];
#pragma unroll
        for (int mt = 0; mt < 2; ++mt)
#pragma unroll
            for (int tt = 0; tt < 4; ++tt) acc2[mt][tt] = (f32x4){0.f, 0.f, 0.f, 0.f};

#pragma unroll
        for (int chunk = 0; chunk < 2; ++chunk) {
            {
                int c = t >> 2, seg = t & 3;
                *(s16x8*)&Bh[c * 40 + seg * 8] = *(const s16x8*)&WpN_hi[(size_t)c * 64 + chunk * 32 + seg * 8];
                *(s16x8*)&Bl[c * 40 + seg * 8] = *(const s16x8*)&WpN_lo[(size_t)c * 64 + chunk * 32 + seg * 8];
            }
            if (wn == chunk) {
#pragma unroll
                for (int mt = 0; mt < 2; ++mt)
#pragma unroll
                    for (int cg = 0; cg < 2; ++cg) {
                        int lc = cg * 16 + l16;
#pragma unroll
                        for (int r = 0; r < 4; ++r) {
                            int rl = wm * 32 + mt * 16 + quad * 4 + r;
                            float v = hv[mt][cg][r];
                            u16 hi = f2bf(v);
                            Ah[rl * 40 + lc] = hi;
                            Al[rl * 40 + lc] = f2bf(v - bf2f(hi));
                        }
                    }
            }
            __syncthreads();

            s16x8 ah[2], al[2];
#pragma unroll
            for (int mt = 0; mt < 2; ++mt) {
                int r = wm * 32 + mt * 16 + l16;
                ah[mt] = *(s16x8*)&Ah[r * 40 + quad * 8];
                al[mt] = *(s16x8*)&Al[r * 40 + quad * 8];
            }
#pragma unroll
            for (int tt = 0; tt < 4; ++tt) {
                int cc = wn * 64 + tt * 16 + l16;
                s16x8 bh = *(s16x8*)&Bh[cc * 40 + quad * 8];
                s16x8 bl = *(s16x8*)&Bl[cc * 40 + quad * 8];
#pragma unroll
                for (int mt = 0; mt < 2; ++mt) {
                    acc2[mt][tt] = MFMA(ah[mt], bh, acc2[mt][tt]);
                    acc2[mt][tt] = MFMA(ah[mt], bl, acc2[mt][tt]);
                    if (wn == 0) acc2[mt][tt] = MFMA(al[mt], bh, acc2[mt][tt]);
                }
            }
            __syncthreads();
        }

#pragma unroll
        for (int mt = 0; mt < 2; ++mt)
#pragma unroll
            for (int tt = 0; tt < 4; ++tt) {
                int col = wn * 64 + tt * 16 + l16;
#pragma unroll
                for (int r = 0; r < 4; ++r) {
                    int row = rows0 + wm * 32 + mt * 16 + quad * 4 + r;
                    if (row >= M) continue;
                    float v = acc2[mt][tt][r];
                    if (col < 64) PhN[(size_t)row * 64 + col] = f2bf(v + pre_bN[col]);
                    else          QhN[(size_t)row * 64 + (col - 64)] = f2bf(v);
                }
            }
    }
}

// ---------------- launch ----------------

extern "C" void kernel_launch(void* const* d_in, const int* in_sizes, int n_in,
                              void* d_out, int out_size, void* d_ws, size_t ws_size,
                              hipStream_t stream) {
    const float* x      = (const float*)d_in[0];
    const int*   ei     = (const int*)d_in[1];
    const float* pre_w  = (const float*)d_in[2];
    const float* pre_b  = (const float*)d_in[3];
    const float* post_w = (const float*)d_in[4];
    const float* post_b = (const float*)d_in[5];
    const float* lin_w  = (const float*)d_in[6];
    const float* lin_b  = (const float*)d_in[7];

    const int N = in_sizes[0] / 64;
    const int E = in_sizes[1] / 2;
    const int L = in_sizes[2] / (128 * 64);

    const int* srcIdx = ei;
    const int* dstIdx = ei + E;

    char* ws = (char*)d_ws;
    size_t off = 0;
    auto alloc = [&](size_t bytes) {
        void* p = ws + off;
        off += (bytes + 255) & ~(size_t)255;
        return p;
    };
    int*      deg        = (int*)alloc((size_t)N * 4);
    int*      offs       = (int*)alloc((size_t)(N + 1) * 4);
    u16*      srcSorted  = (u16*)alloc((size_t)NBP * CAPS * 2);
    unsigned* edgeTmp    = (unsigned*)alloc((size_t)NBP * CAP * 4);
    int*      bucketCur  = (int*)alloc(NBP * 4);
    float*    lsum       = (float*)alloc(256);
    u16*      WpT_hi     = (u16*)alloc((size_t)L * 128 * 64 * 2);
    u16*      WpT_lo     = (u16*)alloc((size_t)L * 128 * 64 * 2);
    u16*      WT_hi      = (u16*)alloc((size_t)L * 192 * 320 * 2);
    u16*      WT_lo      = (u16*)alloc((size_t)L * 192 * 320 * 2);
    float*    bpp        = (float*)alloc((size_t)L * 64 * 4);
    u16*      Ph         = (u16*)alloc((size_t)N * 64 * 2);
    u16*      Qh         = (u16*)alloc((size_t)N * 64 * 2);
    u16*      AGGh       = (u16*)alloc((size_t)N * 256 * 2);
    float*    hA         = (float*)alloc((size_t)N * 64 * 4);
    float*    hB         = (float*)alloc((size_t)N * 64 * 4);
    (void)ws_size;

    int NB = (N + 255) >> 8;
    int NB1 = (E + EPB3 - 1) / EPB3;
    int gblk = (N + 63) / 64;
    int gblk2 = (N + 127) / 128;

    hipMemsetAsync(bucketCur, 0, NBP * 4, stream);
    hipMemsetAsync(lsum, 0, 4, stream);

    k_pre1<<<NB1 + 449 * L, 512, 0, stream>>>(
        srcIdx, dstIdx, E, bucketCur, edgeTmp,
        pre_w, post_w, post_b, lin_w, lin_b,
        WpT_hi, WpT_lo, WT_hi, WT_lo, bpp, NB1);

    k_pre2<<<NB + gblk, 512, 0, stream>>>(
        edgeTmp, bucketCur, deg, offs, lsum, srcSorted,
        x, WpT_hi, WpT_lo, pre_b, Ph, Qh, N, E, NB);

    const float* hIn = x;
    float* hbuf[2] = {hA, hB};
    for (int l = 0; l < L; ++l) {
        float* hOut = (l == L - 1) ? (float*)d_out : hbuf[l & 1];
        int dn = (l < L - 1) ? 1 : 0;
        int ln = dn ? (l + 1) : 0;
        k_agg<<<(N + 15) / 16, 256, 0, stream>>>(Ph, Qh, offs, deg, srcSorted, AGGh, N);
        k_gemm2<<<gblk2, 512, 0, stream>>>(hIn, AGGh,
                                           WT_hi + (size_t)l * 192 * 320,
                                           WT_lo + (size_t)l * 192 * 320,
                                           bpp + (size_t)l * 64,
                                           deg, lsum, hOut, dn,
                                           WpT_hi + (size_t)ln * 128 * 64,
                                           WpT_lo + (size_t)ln * 128 * 64,
                                           pre_b + (size_t)ln * 64,
                                           Ph, Qh, N);
        hIn = hOut;
    }
}